// Round 2
// 10859.656 us; speedup vs baseline: 1.3511x; 1.3511x over previous
//
#include <hip/hip_runtime.h>

typedef unsigned short ushort_t;
typedef float  f32x4  __attribute__((ext_vector_type(4)));
typedef __bf16 bf16x8 __attribute__((ext_vector_type(8)));

// Problem sizes (fixed): B=64, S=512, D=1024, H=1024, 4H=4096
#define NB   64
#define NS   512
#define ND   1024
#define NH   1024
#define NG   4096   // 4*H
#define WPAD 1032   // 1024 + 8: keeps ds_read_b128 16B-aligned, breaks bank stride

// ---------- helpers ----------
__device__ __forceinline__ ushort_t f2bf(float f) {
  unsigned u = __float_as_uint(f);
  u += 0x7FFFu + ((u >> 16) & 1u);   // round-to-nearest-even
  return (ushort_t)(u >> 16);
}
__device__ __forceinline__ float bf2f(ushort_t u) {
  return __uint_as_float(((unsigned)u) << 16);
}
__device__ __forceinline__ float sigmoid_f(float x) {
  return 1.0f / (1.0f + __expf(-x));
}
__device__ __forceinline__ float tanh_f(float x) {
  return 1.0f - 2.0f / (__expf(2.0f * x) + 1.0f);
}

// ---------- prep: fp32 -> bf16 conversions ----------
__global__ __launch_bounds__(256) void cvt_x_kernel(const float4* __restrict__ x,
                                                    ushort_t* __restrict__ xb) {
  int i = blockIdx.x * 256 + threadIdx.x;
  float4 v = x[i];
  ushort4 o;
  o.x = f2bf(v.x); o.y = f2bf(v.y); o.z = f2bf(v.z); o.w = f2bf(v.w);
  *(ushort4*)(xb + (size_t)i * 4) = o;
}

__global__ __launch_bounds__(256) void cvt_w_kernel(const float4* __restrict__ W,
                                                    ushort_t* __restrict__ Wx,
                                                    ushort_t* __restrict__ Wh) {
  int i = blockIdx.x * 256 + threadIdx.x;
  float4 v = W[i];
  int e = i * 4;
  int n = e >> 11;        // row of W  (2048 cols)
  int c = e & 2047;       // col of W
  ushort4 o;
  o.x = f2bf(v.x); o.y = f2bf(v.y); o.z = f2bf(v.z); o.w = f2bf(v.w);
  ushort_t* dst = (c < ND) ? (Wx + (size_t)n * ND + c)
                           : (Wh + (size_t)n * NH + (c - ND));
  *(ushort4*)dst = o;
}

// ---------- pre-GEMM: PG[t][b][n] = x @ Wx^T + bias  (bf16 out) ----------
__global__ __launch_bounds__(256) void pregemm_kernel(
    const ushort_t* __restrict__ xb, const ushort_t* __restrict__ Wx,
    const float* __restrict__ bias, ushort_t* __restrict__ PG) {
  int bid  = blockIdx.x;
  int mblk = bid >> 5;        // 256 m-blocks
  int nblk = bid & 31;        // 32 n-blocks
  int tid  = threadIdx.x;
  int lane = tid & 63, w = tid >> 6;
  int l15  = lane & 15, q = lane >> 4;
  int row0 = mblk * 128 + (w >> 1) * 64;
  int col0 = nblk * 128 + (w & 1) * 64;
  const ushort_t* aBase = xb + (size_t)(row0 + l15) * ND + q * 8;
  const ushort_t* bBase = Wx + (size_t)(col0 + l15) * ND + q * 8;

  f32x4 acc[4][4] = {};
#pragma unroll 2
  for (int k0 = 0; k0 < ND; k0 += 32) {
    bf16x8 a[4], b[4];
#pragma unroll
    for (int mi = 0; mi < 4; ++mi)
      a[mi] = *reinterpret_cast<const bf16x8*>(aBase + (size_t)mi * 16 * ND + k0);
#pragma unroll
    for (int ni = 0; ni < 4; ++ni)
      b[ni] = *reinterpret_cast<const bf16x8*>(bBase + (size_t)ni * 16 * ND + k0);
#pragma unroll
    for (int mi = 0; mi < 4; ++mi)
#pragma unroll
      for (int ni = 0; ni < 4; ++ni)
        acc[mi][ni] = __builtin_amdgcn_mfma_f32_16x16x32_bf16(a[mi], b[ni], acc[mi][ni], 0, 0, 0);
  }
#pragma unroll
  for (int ni = 0; ni < 4; ++ni) {
    int n = col0 + ni * 16 + l15;
    float bv = bias[n];
#pragma unroll
    for (int mi = 0; mi < 4; ++mi) {
#pragma unroll
      for (int r = 0; r < 4; ++r) {
        int m  = row0 + mi * 16 + q * 4 + r;
        int bb = m >> 9;          // batch
        int t  = m & 511;         // time
        PG[((size_t)t * NB + bb) * NG + n] = f2bf(acc[mi][ni][r] + bv);
      }
    }
  }
}

// ---------- recurrent: persistent kernel, single-counter software barrier ----------
// 64 blocks x 1024 thr (16 waves), block owns j in [bid*16, bid*16+16).
// Wh slice (64 rows x 1024) lives in LDS for all 512 steps -> immune to the
// per-step L2 invalidate. h is read straight from global (fresh post-inv).
// Barrier: producer = syncthreads (drain h stores) -> tid0 fetch_add(RELEASE,
// AGENT) [waitcnt + buffer_wbl2 + atomic @ IC]; consumer = tid0 relaxed poll
// cnt >= 64*t -> fence(ACQUIRE,"agent") [buffer_inv] -> syncthreads.
// Guard bound makes ANY barrier failure terminate (~10 s, passed:false),
// never a container-killing hang.
__global__ __launch_bounds__(1024) void lstm_rec_kernel(
    const ushort_t* __restrict__ PG, const ushort_t* __restrict__ Wh,
    ushort_t* hbuf, unsigned* cnt, float* __restrict__ out) {
  __shared__ ushort_t lds_wh[64 * WPAD];    // 132096 B
  __shared__ float lds_g[4][64][17];        // 17408 B   (total 149504 <= 163840)

  int bid = blockIdx.x;                // 0..63
  int j0  = bid * 16;
  int tid = threadIdx.x;
  int lane = tid & 63, w = tid >> 6;
  int g = w & 3, ms = w >> 2;          // wave -> (gate, row-block)
  int l15 = lane & 15, q = lane >> 4;
  int jj = tid & 15, m = tid >> 4;     // cell phase: exactly 1 element/thread

  // one-time: stage Wh slice into LDS (LDS row r = g*16+jr  <->  Wh row g*1024 + j0 + jr)
#pragma unroll
  for (int it = 0; it < 8; ++it) {
    int e   = it * 8192 + tid * 8;     // element index, 16B chunks
    int row = e >> 10;
    int col = e & 1023;
    uint4 v = *(const uint4*)(Wh + ((size_t)((row >> 4) * NH + j0 + (row & 15))) * NH + col);
    *(uint4*)(lds_wh + row * WPAD + col) = v;
  }
  __syncthreads();

  const ushort_t* bBase = lds_wh + (g * 16 + l15) * WPAD + q * 8;
  float c_reg = 0.f;                   // c lives in a register for all 512 steps

  // PG prefetch for t = 0
  ushort_t pg0, pg1, pg2, pg3;
  {
    const ushort_t* pp = PG + (size_t)m * NG + j0 + jj;
    pg0 = pp[0]; pg1 = pp[NH]; pg2 = pp[2 * NH]; pg3 = pp[3 * NH];
  }

  for (int t = 0; t < NS; ++t) {
    if (t > 0) {
      // wait: all 64 blocks have published h_t (cnt >= 64*t)
      if (tid == 0) {
        unsigned tgt = 64u * (unsigned)t;
        int guard = 0;
        while (__hip_atomic_load(cnt, __ATOMIC_RELAXED, __HIP_MEMORY_SCOPE_AGENT) < tgt) {
          if (++guard > (1 << 16)) break;   // terminate loudly, never hang
        }
        __builtin_amdgcn_fence(__ATOMIC_ACQUIRE, "agent");   // buffer_inv: L1/L2 fresh
      }
      __syncthreads();
    }

    // GEMM: 16x16 tile per wave, A (h rows) from global, B (Wh) from LDS
    const ushort_t* hb    = hbuf + (size_t)(t & 1) * (NB * NH);
    const ushort_t* aBase = hb + (size_t)(ms * 16 + l15) * NH + q * 8;
    f32x4 acc = {};
#pragma unroll 8
    for (int k0 = 0; k0 < NH; k0 += 32) {
      bf16x8 av = *reinterpret_cast<const bf16x8*>(aBase + k0);
      bf16x8 bv = *reinterpret_cast<const bf16x8*>(bBase + k0);
      acc = __builtin_amdgcn_mfma_f32_16x16x32_bf16(av, bv, acc, 0, 0, 0);
    }
    // C/D layout: col = lane&15, row = q*4 + r
#pragma unroll
    for (int r = 0; r < 4; ++r)
      lds_g[g][ms * 16 + q * 4 + r][l15] = acc[r];
    __syncthreads();

    // cell: 1 (m, jj) element per thread
    float gi = lds_g[0][m][jj] + bf2f(pg0);
    float gf = lds_g[1][m][jj] + bf2f(pg1);
    float go = lds_g[2][m][jj] + bf2f(pg2);
    float gg = lds_g[3][m][jj] + bf2f(pg3);
    float cn = sigmoid_f(gf) * c_reg + sigmoid_f(gi) * tanh_f(gg);
    float hv = sigmoid_f(go) * tanh_f(cn);
    c_reg = cn;

    ushort_t* hn = hbuf + (size_t)((t & 1) ^ 1) * (NB * NH);
    hn[(size_t)m * NH + j0 + jj] = f2bf(hv);

    if (t == NS - 1) {
      out[((size_t)m * NS + t) * NH + j0 + jj] = hv;
      out[(size_t)NB * NS * NH + (size_t)m * NH + j0 + jj] = hv;                      // final h
      out[(size_t)NB * NS * NH + (size_t)NB * NH + (size_t)m * NH + j0 + jj] = cn;    // final c
    } else {
      __syncthreads();   // drains every wave's hn stores (vmcnt(0) before s_barrier)
      if (tid == 0) {
        // release: waitcnt + buffer_wbl2(sc1) + global_atomic_add(sc1) @ IC
        __hip_atomic_fetch_add(cnt, 1u, __ATOMIC_RELEASE, __HIP_MEMORY_SCOPE_AGENT);
      }
      // off-critical-path work, issued AFTER the signal.
      // out store is NONTEMPORAL: bypasses L2 so the next release-wbl2 does not
      // have to flush 128 KB/block of output on the handshake critical path.
      __builtin_nontemporal_store(hv, &out[((size_t)m * NS + t) * NH + j0 + jj]);
      const ushort_t* pn = PG + ((size_t)(t + 1) * NB + m) * NG + j0 + jj;
      pg0 = pn[0]; pg1 = pn[NH]; pg2 = pn[2 * NH]; pg3 = pn[3 * NH];
    }
  }
}

// ---------- launch ----------
extern "C" void kernel_launch(void* const* d_in, const int* in_sizes, int n_in,
                              void* d_out, int out_size, void* d_ws, size_t ws_size,
                              hipStream_t stream) {
  const float* x    = (const float*)d_in[0];
  const float* W    = (const float*)d_in[1];
  const float* bias = (const float*)d_in[2];
  float* out = (float*)d_out;

  const size_t off_hbuf = 0;                         // 2 * 64*1024 bf16 = 262144
  const size_t off_cnt  = 262144;                    // 1 counter (128 B reserved)
  const size_t off_Wx   = 262272;                    // 8388608
  const size_t off_Wh   = off_Wx + 8388608;          // 8388608
  const size_t off_xb   = off_Wh + 8388608;          // 67108864
  const size_t off_PG   = off_xb + 67108864;         // 268435456
  const size_t need     = off_PG + 268435456;        // ~336.3 MB
  if (ws_size < need) return;

  char* ws = (char*)d_ws;
  ushort_t* hbuf = (ushort_t*)(ws + off_hbuf);
  unsigned* cnt  = (unsigned*)(ws + off_cnt);
  ushort_t* Wx   = (ushort_t*)(ws + off_Wx);
  ushort_t* Wh   = (ushort_t*)(ws + off_Wh);
  ushort_t* xb   = (ushort_t*)(ws + off_xb);
  ushort_t* PG   = (ushort_t*)(ws + off_PG);

  hipMemsetAsync(ws, 0, 262272, stream);   // h0 = 0 and cnt = 0

  cvt_x_kernel<<<32768, 256, 0, stream>>>((const float4*)x, xb);
  cvt_w_kernel<<<8192, 256, 0, stream>>>((const float4*)W, Wx, Wh);
  pregemm_kernel<<<8192, 256, 0, stream>>>(xb, Wx, bias, PG);

  // cooperative launch kept only for the co-residency guarantee (64 blocks)
  void* args[] = { (void*)&PG, (void*)&Wh, (void*)&hbuf, (void*)&cnt, (void*)&out };
  hipLaunchCooperativeKernel((void*)lstm_rec_kernel, dim3(64), dim3(1024),
                             args, 0, stream);
}

// Round 5
// 10534.949 us; speedup vs baseline: 1.3928x; 1.0308x over previous
//
#include <hip/hip_runtime.h>

typedef unsigned short ushort_t;
typedef unsigned long long u64_t;
typedef float  f32x4  __attribute__((ext_vector_type(4)));
typedef __bf16 bf16x8 __attribute__((ext_vector_type(8)));

// Problem sizes (fixed): B=64, S=512, D=1024, H=1024, 4H=4096
#define NB   64
#define NS   512
#define ND   1024
#define NH   1024
#define NG   4096   // 4*H

// ---------- helpers ----------
__device__ __forceinline__ ushort_t f2bf(float f) {
  unsigned u = __float_as_uint(f);
  u += 0x7FFFu + ((u >> 16) & 1u);   // round-to-nearest-even
  return (ushort_t)(u >> 16);
}
__device__ __forceinline__ float bf2f(ushort_t u) {
  return __uint_as_float(((unsigned)u) << 16);
}
__device__ __forceinline__ float sigmoid_f(float x) {
  return 1.0f / (1.0f + __expf(-x));
}
__device__ __forceinline__ float tanh_f(float x) {
  return 1.0f - 2.0f / (__expf(2.0f * x) + 1.0f);
}

// ---------- prep: fp32 -> bf16 conversions ----------
__global__ __launch_bounds__(256) void cvt_x_kernel(const float4* __restrict__ x,
                                                    ushort_t* __restrict__ xb) {
  int i = blockIdx.x * 256 + threadIdx.x;
  float4 v = x[i];
  ushort4 o;
  o.x = f2bf(v.x); o.y = f2bf(v.y); o.z = f2bf(v.z); o.w = f2bf(v.w);
  *(ushort4*)(xb + (size_t)i * 4) = o;
}

__global__ __launch_bounds__(256) void cvt_w_kernel(const float4* __restrict__ W,
                                                    ushort_t* __restrict__ Wx,
                                                    ushort_t* __restrict__ Wh) {
  int i = blockIdx.x * 256 + threadIdx.x;
  float4 v = W[i];
  int e = i * 4;
  int n = e >> 11;        // row of W  (2048 cols)
  int c = e & 2047;       // col of W
  ushort4 o;
  o.x = f2bf(v.x); o.y = f2bf(v.y); o.z = f2bf(v.z); o.w = f2bf(v.w);
  ushort_t* dst = (c < ND) ? (Wx + (size_t)n * ND + c)
                           : (Wh + (size_t)n * NH + (c - ND));
  *(ushort4*)dst = o;
}

// ---------- pre-GEMM: PG[t][b][n] = x @ Wx^T + bias  (bf16 out) ----------
__global__ __launch_bounds__(256) void pregemm_kernel(
    const ushort_t* __restrict__ xb, const ushort_t* __restrict__ Wx,
    const float* __restrict__ bias, ushort_t* __restrict__ PG) {
  int bid  = blockIdx.x;
  int mblk = bid >> 5;        // 256 m-blocks
  int nblk = bid & 31;        // 32 n-blocks
  int tid  = threadIdx.x;
  int lane = tid & 63, w = tid >> 6;
  int l15  = lane & 15, q = lane >> 4;
  int row0 = mblk * 128 + (w >> 1) * 64;
  int col0 = nblk * 128 + (w & 1) * 64;
  const ushort_t* aBase = xb + (size_t)(row0 + l15) * ND + q * 8;
  const ushort_t* bBase = Wx + (size_t)(col0 + l15) * ND + q * 8;

  f32x4 acc[4][4] = {};
#pragma unroll 2
  for (int k0 = 0; k0 < ND; k0 += 32) {
    bf16x8 a[4], b[4];
#pragma unroll
    for (int mi = 0; mi < 4; ++mi)
      a[mi] = *reinterpret_cast<const bf16x8*>(aBase + (size_t)mi * 16 * ND + k0);
#pragma unroll
    for (int ni = 0; ni < 4; ++ni)
      b[ni] = *reinterpret_cast<const bf16x8*>(bBase + (size_t)ni * 16 * ND + k0);
#pragma unroll
    for (int mi = 0; mi < 4; ++mi)
#pragma unroll
      for (int ni = 0; ni < 4; ++ni)
        acc[mi][ni] = __builtin_amdgcn_mfma_f32_16x16x32_bf16(a[mi], b[ni], acc[mi][ni], 0, 0, 0);
  }
#pragma unroll
  for (int ni = 0; ni < 4; ++ni) {
    int n = col0 + ni * 16 + l15;
    float bv = bias[n];
#pragma unroll
    for (int mi = 0; mi < 4; ++mi) {
#pragma unroll
      for (int r = 0; r < 4; ++r) {
        int m  = row0 + mi * 16 + q * 4 + r;
        int bb = m >> 9;          // batch
        int t  = m & 511;         // time
        PG[((size_t)t * NB + bb) * NG + n] = f2bf(acc[mi][ni][r] + bv);
      }
    }
  }
}

// ---------- recurrent: persistent kernel, fence-free IC exchange ----------
// 64 blocks x 1024 thr (16 waves), block owns j in [bid*16, bid*16+16).
// Cross-XCD data (h + counter) moves via Infinity Cache ONLY, using
// compiler-generated relaxed agent-scope atomics (emit sc0 sc1 ops):
//   h stores: 32-bit atomic store  -> write-through, L2 never dirty
//   h loads:  64-bit atomic load   -> bypass L1/L2, no stale copy forms
//   counter:  relaxed fetch_add / load
// => no buffer_wbl2 / buffer_inv (full-L2 tag walks) anywhere in the loop.
// Wh is read-only through normal cached loads: L2 is never invalidated, so
// each block's 128 KB Wh slice stays L2-resident for all 512 steps.
// Ordering: h stores -> __syncthreads (vmcnt(0) drain before s_barrier is
// compiler-guaranteed) -> tid0 fetch_add. Consumer: tid0 guard-bounded poll
// -> __syncthreads. Any protocol failure terminates loudly (passed:false).
// r5 fix: staging is 16 x u64 per thread (16*1024*8 = 128 KB = full h);
// r4 had 8 iters -> rows 32..63 never staged -> NaN from uninitialized LDS.
__global__ __launch_bounds__(1024) void lstm_rec_kernel(
    const ushort_t* __restrict__ PG, const ushort_t* __restrict__ Wh,
    ushort_t* hbuf, unsigned* cnt, float* __restrict__ out) {
  __shared__ ushort_t lds_h[64 * 1024];     // 131072 B, XOR-swizzled rows
  __shared__ float lds_g[4][64][17];        // 17408 B   (total 148480 <= 163840)

  int bid = blockIdx.x;                // 0..63
  int j0  = bid * 16;
  int tid = threadIdx.x;
  int lane = tid & 63, w = tid >> 6;
  int g = w & 3, ms = w >> 2;          // wave -> (gate, row-block)
  int l15 = lane & 15, q = lane >> 4;
  int jj = tid & 15, m = tid >> 4;     // cell phase: exactly 1 element/thread

  // B operand (Wh) straight from global: L2-resident, never invalidated
  const ushort_t* bB = Wh + (size_t)(g * NH + j0 + l15) * NH + q * 8;

  // A-fragment LDS geometry (swizzled: byte ^= (row&7)<<4, write & read side)
  int rowA = ms * 16 + l15;
  int swA  = (rowA & 7) << 4;
  const char* aRow = (const char*)lds_h + rowA * 2048;

  float c_reg = 0.f;                   // c lives in a register for all 512 steps

  // PG prefetch for t = 0 (nontemporal: don't evict Wh from L2)
  ushort_t pg0, pg1, pg2, pg3;
  {
    const ushort_t* pp = PG + (size_t)m * NG + j0 + jj;
    pg0 = __builtin_nontemporal_load(pp);
    pg1 = __builtin_nontemporal_load(pp + NH);
    pg2 = __builtin_nontemporal_load(pp + 2 * NH);
    pg3 = __builtin_nontemporal_load(pp + 3 * NH);
  }

  for (int t = 0; t < NS; ++t) {
    // ---- wait: all 64 blocks published h_t (cnt >= 64*t)
    if (t > 0) {
      if (tid == 0) {
        unsigned tgt = 64u * (unsigned)t;
        int guard = 0;
        while (__hip_atomic_load(cnt, __ATOMIC_RELAXED, __HIP_MEMORY_SCOPE_AGENT) < tgt) {
          if (++guard > (1 << 14)) break;   // terminate loudly, never hang
        }
      }
      __builtin_amdgcn_sched_barrier(0);
      __syncthreads();
    }

    // ---- stage h_t into LDS via IC (relaxed agent atomic loads = sc0 sc1,
    // bypass possibly-stale L1/L2 -> no cache invalidate ever needed).
    // 16 iters x 1024 thr x 8 B = 131072 B = full 64x1024 bf16 h matrix.
    {
      const u64_t* hb64 = (const u64_t*)(hbuf + (size_t)(t & 1) * (NB * NH));
      u64_t hv8[16];
#pragma unroll
      for (int it = 0; it < 16; ++it)
        hv8[it] = __hip_atomic_load(hb64 + it * 1024 + tid,
                                    __ATOMIC_RELAXED, __HIP_MEMORY_SCOPE_AGENT);
#pragma unroll
      for (int it = 0; it < 16; ++it) {
        int idx  = it * 1024 + tid;     // 8-byte chunk index within h (64 rows x 256)
        int row  = idx >> 8;
        int colB = (idx & 255) * 8;
        *(u64_t*)((char*)lds_h + row * 2048 + (colB ^ ((row & 7) << 4))) = hv8[it];
      }
    }
    __syncthreads();

    // ---- GEMM: 16x16 tile per wave, A (h) from swizzled LDS, B (Wh) from L2
    f32x4 acc = {};
#pragma unroll 8
    for (int k0 = 0; k0 < NH; k0 += 32) {
      bf16x8 av = *(const bf16x8*)(aRow + ((16 * q + 2 * k0) ^ swA));
      bf16x8 bv = *reinterpret_cast<const bf16x8*>(bB + k0);
      acc = __builtin_amdgcn_mfma_f32_16x16x32_bf16(av, bv, acc, 0, 0, 0);
    }
    // C/D layout: col = lane&15, row = q*4 + r
#pragma unroll
    for (int r = 0; r < 4; ++r)
      lds_g[g][ms * 16 + q * 4 + r][l15] = acc[r];
    __syncthreads();

    // ---- cell: 1 (m, jj) element per thread
    float gi = lds_g[0][m][jj] + bf2f(pg0);
    float gf = lds_g[1][m][jj] + bf2f(pg1);
    float go = lds_g[2][m][jj] + bf2f(pg2);
    float gg = lds_g[3][m][jj] + bf2f(pg3);
    float cn = sigmoid_f(gf) * c_reg + sigmoid_f(gi) * tanh_f(gg);
    float hv = sigmoid_f(go) * tanh_f(cn);
    c_reg = cn;

    // publish h_{t+1}: pack 2 bf16, even threads do one 32-bit agent atomic
    // store (write-through to IC; never dirties L2)
    unsigned my16 = (unsigned)f2bf(hv);
    unsigned nb16 = (unsigned)__shfl_down((int)my16, 1);
    if (t == NS - 1) {
      out[((size_t)m * NS + t) * NH + j0 + jj] = hv;
      out[(size_t)NB * NS * NH + (size_t)m * NH + j0 + jj] = hv;                      // final h
      out[(size_t)NB * NS * NH + (size_t)NB * NH + (size_t)m * NH + j0 + jj] = cn;    // final c
    } else {
      if ((tid & 1) == 0) {
        unsigned* hn32 = (unsigned*)(hbuf + (size_t)((t & 1) ^ 1) * (NB * NH));
        __hip_atomic_store(hn32 + m * (NH / 2) + ((j0 + jj) >> 1),
                           my16 | (nb16 << 16),
                           __ATOMIC_RELAXED, __HIP_MEMORY_SCOPE_AGENT);
      }
      __syncthreads();   // vmcnt(0) drain of every wave's h store, then barrier
      if (tid == 0)
        __hip_atomic_fetch_add(cnt, 1u, __ATOMIC_RELAXED, __HIP_MEMORY_SCOPE_AGENT);
      // off-critical-path: out store (nt) + PG prefetch for t+1
      __builtin_nontemporal_store(hv, &out[((size_t)m * NS + t) * NH + j0 + jj]);
      const ushort_t* pn = PG + ((size_t)(t + 1) * NB + m) * NG + j0 + jj;
      pg0 = __builtin_nontemporal_load(pn);
      pg1 = __builtin_nontemporal_load(pn + NH);
      pg2 = __builtin_nontemporal_load(pn + 2 * NH);
      pg3 = __builtin_nontemporal_load(pn + 3 * NH);
    }
  }
}

// ---------- launch ----------
extern "C" void kernel_launch(void* const* d_in, const int* in_sizes, int n_in,
                              void* d_out, int out_size, void* d_ws, size_t ws_size,
                              hipStream_t stream) {
  const float* x    = (const float*)d_in[0];
  const float* W    = (const float*)d_in[1];
  const float* bias = (const float*)d_in[2];
  float* out = (float*)d_out;

  const size_t off_hbuf = 0;                         // 2 * 64*1024 bf16 = 262144
  const size_t off_cnt  = 262144;                    // 1 counter (128 B reserved)
  const size_t off_Wx   = 262272;                    // 8388608
  const size_t off_Wh   = off_Wx + 8388608;          // 8388608
  const size_t off_xb   = off_Wh + 8388608;          // 67108864
  const size_t off_PG   = off_xb + 67108864;         // 268435456
  const size_t need     = off_PG + 268435456;        // ~336.3 MB
  if (ws_size < need) return;

  char* ws = (char*)d_ws;
  ushort_t* hbuf = (ushort_t*)(ws + off_hbuf);
  unsigned* cnt  = (unsigned*)(ws + off_cnt);
  ushort_t* Wx   = (ushort_t*)(ws + off_Wx);
  ushort_t* Wh   = (ushort_t*)(ws + off_Wh);
  ushort_t* xb   = (ushort_t*)(ws + off_xb);
  ushort_t* PG   = (ushort_t*)(ws + off_PG);

  hipMemsetAsync(ws, 0, 262272, stream);   // h0 = 0 and cnt = 0

  cvt_x_kernel<<<32768, 256, 0, stream>>>((const float4*)x, xb);
  cvt_w_kernel<<<8192, 256, 0, stream>>>((const float4*)W, Wx, Wh);
  pregemm_kernel<<<8192, 256, 0, stream>>>(xb, Wx, bias, PG);

  // cooperative launch kept only for the co-residency guarantee (64 blocks)
  void* args[] = { (void*)&PG, (void*)&Wh, (void*)&hbuf, (void*)&cnt, (void*)&out };
  hipLaunchCooperativeKernel((void*)lstm_rec_kernel, dim3(64), dim3(1024),
                             args, 0, stream);
}

// Round 6
// 9532.896 us; speedup vs baseline: 1.5392x; 1.1051x over previous
//
#include <hip/hip_runtime.h>

typedef unsigned short ushort_t;
typedef unsigned long long u64_t;
typedef float  f32x4  __attribute__((ext_vector_type(4)));
typedef __bf16 bf16x8 __attribute__((ext_vector_type(8)));

// Problem sizes (fixed): B=64, S=512, D=1024, H=1024, 4H=4096
#define NB   64
#define NS   512
#define ND   1024
#define NH   1024
#define NG   4096   // 4*H

// ---------- helpers ----------
__device__ __forceinline__ ushort_t f2bf(float f) {
  unsigned u = __float_as_uint(f);
  u += 0x7FFFu + ((u >> 16) & 1u);   // round-to-nearest-even
  return (ushort_t)(u >> 16);
}
__device__ __forceinline__ float bf2f(ushort_t u) {
  return __uint_as_float(((unsigned)u) << 16);
}
__device__ __forceinline__ float sigmoid_f(float x) {
  return 1.0f / (1.0f + __expf(-x));
}
__device__ __forceinline__ float tanh_f(float x) {
  return 1.0f - 2.0f / (__expf(2.0f * x) + 1.0f);
}

// ---------- prep: fp32 -> bf16 conversions ----------
__global__ __launch_bounds__(256) void cvt_x_kernel(const float4* __restrict__ x,
                                                    ushort_t* __restrict__ xb) {
  int i = blockIdx.x * 256 + threadIdx.x;
  float4 v = x[i];
  ushort4 o;
  o.x = f2bf(v.x); o.y = f2bf(v.y); o.z = f2bf(v.z); o.w = f2bf(v.w);
  *(ushort4*)(xb + (size_t)i * 4) = o;
}

__global__ __launch_bounds__(256) void cvt_w_kernel(const float4* __restrict__ W,
                                                    ushort_t* __restrict__ Wx,
                                                    ushort_t* __restrict__ Wh) {
  int i = blockIdx.x * 256 + threadIdx.x;
  float4 v = W[i];
  int e = i * 4;
  int n = e >> 11;        // row of W  (2048 cols)
  int c = e & 2047;       // col of W
  ushort4 o;
  o.x = f2bf(v.x); o.y = f2bf(v.y); o.z = f2bf(v.z); o.w = f2bf(v.w);
  ushort_t* dst = (c < ND) ? (Wx + (size_t)n * ND + c)
                           : (Wh + (size_t)n * NH + (c - ND));
  *(ushort4*)dst = o;
}

// ---------- pre-GEMM: PG[t][b][n] = x @ Wx^T + bias  (bf16 out) ----------
__global__ __launch_bounds__(256) void pregemm_kernel(
    const ushort_t* __restrict__ xb, const ushort_t* __restrict__ Wx,
    const float* __restrict__ bias, ushort_t* __restrict__ PG) {
  int bid  = blockIdx.x;
  int mblk = bid >> 5;        // 256 m-blocks
  int nblk = bid & 31;        // 32 n-blocks
  int tid  = threadIdx.x;
  int lane = tid & 63, w = tid >> 6;
  int l15  = lane & 15, q = lane >> 4;
  int row0 = mblk * 128 + (w >> 1) * 64;
  int col0 = nblk * 128 + (w & 1) * 64;
  const ushort_t* aBase = xb + (size_t)(row0 + l15) * ND + q * 8;
  const ushort_t* bBase = Wx + (size_t)(col0 + l15) * ND + q * 8;

  f32x4 acc[4][4] = {};
#pragma unroll 2
  for (int k0 = 0; k0 < ND; k0 += 32) {
    bf16x8 a[4], b[4];
#pragma unroll
    for (int mi = 0; mi < 4; ++mi)
      a[mi] = *reinterpret_cast<const bf16x8*>(aBase + (size_t)mi * 16 * ND + k0);
#pragma unroll
    for (int ni = 0; ni < 4; ++ni)
      b[ni] = *reinterpret_cast<const bf16x8*>(bBase + (size_t)ni * 16 * ND + k0);
#pragma unroll
    for (int mi = 0; mi < 4; ++mi)
#pragma unroll
      for (int ni = 0; ni < 4; ++ni)
        acc[mi][ni] = __builtin_amdgcn_mfma_f32_16x16x32_bf16(a[mi], b[ni], acc[mi][ni], 0, 0, 0);
  }
#pragma unroll
  for (int ni = 0; ni < 4; ++ni) {
    int n = col0 + ni * 16 + l15;
    float bv = bias[n];
#pragma unroll
    for (int mi = 0; mi < 4; ++mi) {
#pragma unroll
      for (int r = 0; r < 4; ++r) {
        int m  = row0 + mi * 16 + q * 4 + r;
        int bb = m >> 9;          // batch
        int t  = m & 511;         // time
        PG[((size_t)t * NB + bb) * NG + n] = f2bf(acc[mi][ni][r] + bv);
      }
    }
  }
}

// ---------- recurrent: 4 independent machines of 16 blocks ----------
// Batch recurrences are independent (weights shared, FLOPs scale per-batch),
// so machine m = bid>>4 owns batches [m*16, m*16+16) with its OWN h buffers
// and its OWN 16-participant barrier. Block slot s = bid&15 owns j-columns
// [s*64, s*64+64), all 4 gates. Wave w = (g=w&3, jb=w>>2): 16(batch)x16(j)
// tile of gate g, K=1024, 32 MFMAs.
// Barrier per machine: NO atomic RMW. Each block plain-stores step# to its
// own flag line (agent scope, sc0 sc1 -> IC); wave 0 polls the machine's 16
// flag lines in parallel (4 lanes/line). Arrivals 64->16, skew max-over-16,
// machines fully decoupled. h exchange: 32 KB/machine via IC (relaxed agent
// atomics, no L2 state => no cache-maintenance fences anywhere -- r5-proven).
__global__ __launch_bounds__(1024) void lstm_rec_kernel(
    const ushort_t* __restrict__ PG, const ushort_t* __restrict__ Wh,
    ushort_t* hbuf, unsigned* flags, float* __restrict__ out) {
  __shared__ ushort_t lds_h[16 * 1024];     // 32768 B, batch-major, XOR-swizzled
  __shared__ float lds_g[4][16][66];        // 16896 B  (total ~49.7 KB)

  int bid  = blockIdx.x;
  int mach = bid >> 4;                 // 0..3  machine (16 batches)
  int slot = bid & 15;                 // 0..15 j-slot (64 columns)
  int tid  = threadIdx.x;
  int lane = tid & 63, w = tid >> 6;
  int g = w & 3, jb = w >> 2;          // wave -> (gate, 16-col j-block)
  int l15 = lane & 15, q = lane >> 4;
  int mb = tid >> 6, jc = tid & 63;    // cell phase: (batch, j-col) per thread

  // machine-local h double buffers: 16 x 1024 bf16 = 32 KB each
  ushort_t* hm0 = hbuf + (size_t)(mach * 2) * (16 * NH);
  ushort_t* hm1 = hm0 + 16 * NH;

  // B operand (Wh) from global: L2-resident (L2 never invalidated)
  const ushort_t* bB =
      Wh + (size_t)(g * NH + slot * 64 + jb * 16 + l15) * NH + q * 8;

  // A-fragment LDS geometry: row = batch = l15, swizzle byte ^= (row&7)<<4
  int swA = (l15 & 7) << 4;
  const char* aRow = (const char*)lds_h + l15 * 2048;

  unsigned* myflag = flags + (size_t)(mach * 16 + slot) * 32;  // 128 B apart
  float c_reg = 0.f;                   // c lives in a register for all 512 steps

  int bglob = mach * 16 + mb;          // global batch of this thread's cell elem
  int jglob = slot * 64 + jc;          // global j-column

  // PG prefetch for t = 0 (nontemporal: don't evict Wh from L2)
  ushort_t pg0, pg1, pg2, pg3;
  {
    const ushort_t* pp = PG + (size_t)bglob * NG + jglob;
    pg0 = __builtin_nontemporal_load(pp);
    pg1 = __builtin_nontemporal_load(pp + NH);
    pg2 = __builtin_nontemporal_load(pp + 2 * NH);
    pg3 = __builtin_nontemporal_load(pp + 3 * NH);
  }

  for (int t = 0; t < NS; ++t) {
    // ---- wait: all 16 blocks of THIS machine published h_t
    if (t > 0) {
      if (w == 0) {
        unsigned tgt = (unsigned)t;
        const unsigned* fp = flags + (size_t)(mach * 16 + (lane & 15)) * 32;
        int guard = 0;
        for (;;) {
          unsigned v = __hip_atomic_load(fp, __ATOMIC_RELAXED,
                                         __HIP_MEMORY_SCOPE_AGENT);
          if (__all(v >= tgt)) break;
          if (++guard > (1 << 14)) break;   // terminate loudly, never hang
        }
      }
      __builtin_amdgcn_sched_barrier(0);
      __syncthreads();
    }

    // ---- stage machine's h_t into LDS via IC (relaxed agent = sc0 sc1,
    // bypasses possibly-stale L1/L2). 4 x 1024 x 8 B = 32768 B = full 16x1024.
    {
      const u64_t* hb64 =
          (const u64_t*)((t & 1) ? hm1 : hm0);
      u64_t hv8[4];
#pragma unroll
      for (int it = 0; it < 4; ++it)
        hv8[it] = __hip_atomic_load(hb64 + it * 1024 + tid,
                                    __ATOMIC_RELAXED, __HIP_MEMORY_SCOPE_AGENT);
#pragma unroll
      for (int it = 0; it < 4; ++it) {
        int idx  = it * 1024 + tid;     // 8-byte chunk index (16 rows x 256)
        int row  = idx >> 8;
        int colB = (idx & 255) * 8;
        *(u64_t*)((char*)lds_h + row * 2048 + (colB ^ ((row & 7) << 4))) = hv8[it];
      }
    }
    __syncthreads();

    // ---- GEMM: 16(batch)x16(j) tile per wave, A from swizzled LDS, B from L2
    f32x4 acc = {};
#pragma unroll 8
    for (int k0 = 0; k0 < NH; k0 += 32) {
      bf16x8 av = *(const bf16x8*)(aRow + ((16 * q + 2 * k0) ^ swA));
      bf16x8 bv = *reinterpret_cast<const bf16x8*>(bB + k0);
      acc = __builtin_amdgcn_mfma_f32_16x16x32_bf16(av, bv, acc, 0, 0, 0);
    }
    // C/D layout: col(l15) = B-row = j-within-16, row(q*4+r) = A-row = batch
#pragma unroll
    for (int r = 0; r < 4; ++r)
      lds_g[g][q * 4 + r][jb * 16 + l15] = acc[r];
    __syncthreads();

    // ---- cell: 1 (mb, jc) element per thread
    float gi = lds_g[0][mb][jc] + bf2f(pg0);
    float gf = lds_g[1][mb][jc] + bf2f(pg1);
    float go = lds_g[2][mb][jc] + bf2f(pg2);
    float gg = lds_g[3][mb][jc] + bf2f(pg3);
    float cn = sigmoid_f(gf) * c_reg + sigmoid_f(gi) * tanh_f(gg);
    float hv = sigmoid_f(go) * tanh_f(cn);
    c_reg = cn;

    // publish h_{t+1}: pack 2 bf16 (adjacent jc), even threads store one u32
    // agent-scope (write-through to IC; never dirties L2)
    unsigned my16 = (unsigned)f2bf(hv);
    unsigned nb16 = (unsigned)__shfl_down((int)my16, 1);
    if (t == NS - 1) {
      out[((size_t)bglob * NS + t) * NH + jglob] = hv;
      out[(size_t)NB * NS * NH + (size_t)bglob * NH + jglob] = hv;                    // final h
      out[(size_t)NB * NS * NH + (size_t)NB * NH + (size_t)bglob * NH + jglob] = cn;  // final c
    } else {
      if ((tid & 1) == 0) {
        unsigned* hn32 = (unsigned*)((t & 1) ? hm0 : hm1);
        __hip_atomic_store(hn32 + mb * 512 + slot * 32 + (jc >> 1),
                           my16 | (nb16 << 16),
                           __ATOMIC_RELAXED, __HIP_MEMORY_SCOPE_AGENT);
      }
      __syncthreads();   // vmcnt(0) drain of every wave's h store, then barrier
      if (tid == 0)
        __hip_atomic_store(myflag, (unsigned)(t + 1),
                           __ATOMIC_RELAXED, __HIP_MEMORY_SCOPE_AGENT);
      // off-critical-path: out store (nt) + PG prefetch for t+1
      __builtin_nontemporal_store(hv, &out[((size_t)bglob * NS + t) * NH + jglob]);
      const ushort_t* pn = PG + ((size_t)(t + 1) * NB + bglob) * NG + jglob;
      pg0 = __builtin_nontemporal_load(pn);
      pg1 = __builtin_nontemporal_load(pn + NH);
      pg2 = __builtin_nontemporal_load(pn + 2 * NH);
      pg3 = __builtin_nontemporal_load(pn + 3 * NH);
    }
  }
}

// ---------- launch ----------
extern "C" void kernel_launch(void* const* d_in, const int* in_sizes, int n_in,
                              void* d_out, int out_size, void* d_ws, size_t ws_size,
                              hipStream_t stream) {
  const float* x    = (const float*)d_in[0];
  const float* W    = (const float*)d_in[1];
  const float* bias = (const float*)d_in[2];
  float* out = (float*)d_out;

  const size_t off_hbuf  = 0;                        // 4 mach * 2 buf * 32 KB = 262144
  const size_t off_flags = 262144;                   // 64 lines * 128 B = 8192
  const size_t off_Wx    = 270336;                   // 8388608
  const size_t off_Wh    = off_Wx + 8388608;         // 8388608
  const size_t off_xb    = off_Wh + 8388608;         // 67108864
  const size_t off_PG    = off_xb + 67108864;        // 268435456
  const size_t need      = off_PG + 268435456;       // ~336.3 MB
  if (ws_size < need) return;

  char* ws = (char*)d_ws;
  ushort_t* hbuf  = (ushort_t*)(ws + off_hbuf);
  unsigned* flags = (unsigned*)(ws + off_flags);
  ushort_t* Wx    = (ushort_t*)(ws + off_Wx);
  ushort_t* Wh    = (ushort_t*)(ws + off_Wh);
  ushort_t* xb    = (ushort_t*)(ws + off_xb);
  ushort_t* PG    = (ushort_t*)(ws + off_PG);

  hipMemsetAsync(ws, 0, 270336, stream);   // h0 = 0 and flags = 0

  cvt_x_kernel<<<32768, 256, 0, stream>>>((const float4*)x, xb);
  cvt_w_kernel<<<8192, 256, 0, stream>>>((const float4*)W, Wx, Wh);
  pregemm_kernel<<<8192, 256, 0, stream>>>(xb, Wx, bias, PG);

  // cooperative launch kept only for the co-residency guarantee (64 blocks)
  void* args[] = { (void*)&PG, (void*)&Wh, (void*)&hbuf, (void*)&flags, (void*)&out };
  hipLaunchCooperativeKernel((void*)lstm_rec_kernel, dim3(64), dim3(1024),
                             args, 0, stream);
}